// Round 1
// baseline (307.808 us; speedup 1.0000x reference)
//
#include <hip/hip_runtime.h>
#include <stdint.h>

#define B_ 8
#define H_ 128
#define W_ 128
#define D_ 128
#define N_ (H_*W_)
#define M_ (B_*N_)   // 131072 rows total

typedef __attribute__((ext_vector_type(8))) short short8;
typedef __attribute__((ext_vector_type(4))) float floatx4;

__device__ inline unsigned short f2bf(float f){
  union { float f; unsigned int i; } c; c.f = f;
  unsigned int x = c.i;
  x += 0x7FFF + ((x >> 16) & 1);   // RNE
  return (unsigned short)(x >> 16);
}
__device__ inline float bf2f(unsigned short u){
  union { unsigned int i; float f; } c; c.i = ((unsigned int)u) << 16; return c.f;
}

// ---------------- kernel 0: W -> W^T bf16  ([k][n] fp32 -> [n][k] bf16) ----------------
__global__ void wtrans_kernel(const float* __restrict__ Wq, const float* __restrict__ Wk,
                              const float* __restrict__ Wv, unsigned short* __restrict__ Wt){
  const float* src = blockIdx.x == 0 ? Wq : (blockIdx.x == 1 ? Wk : Wv);
  unsigned short* dst = Wt + blockIdx.x * (D_*D_);
  for (int i = threadIdx.x; i < D_*D_; i += blockDim.x){
    int k = i >> 7, n = i & 127;
    dst[n*D_ + k] = f2bf(src[i]);
  }
}

// ---------------- kernel 1: QKV projection, bf16 MFMA 128x128 tile ----------------
// grid (3, M/128); block 256 (4 waves); each wave does a 64x64 quadrant (4x4 of 16x16)
__global__ __launch_bounds__(256, 2) void qkv_gemm_kernel(
    const float* __restrict__ x, const unsigned short* __restrict__ Wt,
    const float* __restrict__ bq, const float* __restrict__ bk, const float* __restrict__ bv,
    unsigned short* __restrict__ Q, unsigned short* __restrict__ K, unsigned short* __restrict__ V)
{
  const int which = blockIdx.x;          // 0=Q 1=K 2=V (fastest dim -> x-tile L2 reuse)
  const int rowTile = blockIdx.y;
  const float* bias = which == 0 ? bq : (which == 1 ? bk : bv);
  unsigned short* Out = which == 0 ? Q : (which == 1 ? K : V);
  const unsigned short* Wsel = Wt + which * (D_*D_);

  // +8 bf16 pad (16B) per row: b128 fragment reads land on distinct bank pairs
  __shared__ unsigned short Ash[128][136];
  __shared__ unsigned short Bsh[128][136];

  const int t = threadIdx.x;
  {
    // stage A: x tile 128 rows x 128 K, fp32 -> bf16
    const int chunk = t & 31;            // float4 index within row
    const int r0 = t >> 5;               // 0..7
    #pragma unroll
    for (int p = 0; p < 16; ++p){
      int r = p*8 + r0;
      const float4 f = *(const float4*)(x + ((size_t)(rowTile*128 + r))*D_ + chunk*4);
      unsigned int lo = (unsigned int)f2bf(f.x) | ((unsigned int)f2bf(f.y) << 16);
      unsigned int hi = (unsigned int)f2bf(f.z) | ((unsigned int)f2bf(f.w) << 16);
      uint2 pk; pk.x = lo; pk.y = hi;
      *(uint2*)&Ash[r][chunk*4] = pk;
    }
    // stage B: W^T (already bf16, [n][k]) -> LDS, 16B per thread per pass
    const int col8 = t & 15;
    const int n0 = t >> 4;
    #pragma unroll
    for (int p = 0; p < 8; ++p){
      int n = p*16 + n0;
      uint4 w4 = *(const uint4*)(Wsel + n*D_ + col8*8);
      *(uint4*)&Bsh[n][col8*8] = w4;
    }
  }
  __syncthreads();

  const int wave = t >> 6, lane = t & 63;
  const int wm = (wave >> 1) * 64, wn = (wave & 1) * 64;
  const int m0 = lane & 15, quad = lane >> 4;

  floatx4 acc[4][4] = {};
  #pragma unroll
  for (int kk = 0; kk < 4; ++kk){
    short8 a[4], b[4];
    #pragma unroll
    for (int i = 0; i < 4; ++i)
      a[i] = *(const short8*)&Ash[wm + i*16 + m0][kk*32 + quad*8];
    #pragma unroll
    for (int j = 0; j < 4; ++j)
      b[j] = *(const short8*)&Bsh[wn + j*16 + m0][kk*32 + quad*8];
    #pragma unroll
    for (int i = 0; i < 4; ++i)
      #pragma unroll
      for (int j = 0; j < 4; ++j)
        acc[i][j] = __builtin_amdgcn_mfma_f32_16x16x32_bf16(a[i], b[j], acc[i][j], 0, 0, 0);
  }

  // epilogue: C/D layout col=lane&15, row=quad*4+reg   (m89/m91-verified)
  #pragma unroll
  for (int j = 0; j < 4; ++j){
    const int col = wn + j*16 + m0;
    const float bb = bias[col];
    #pragma unroll
    for (int i = 0; i < 4; ++i){
      #pragma unroll
      for (int r = 0; r < 4; ++r){
        int row = rowTile*128 + wm + i*16 + quad*4 + r;
        Out[(size_t)row * D_ + col] = f2bf(acc[i][j][r] + bb);
      }
    }
  }
}

// ---------------- kernel 2: 3x3 window attention, one wave per pixel ----------------
__global__ __launch_bounds__(256) void attn_kernel(
    const unsigned short* __restrict__ Q, const unsigned short* __restrict__ K,
    const unsigned short* __restrict__ V, float* __restrict__ out)
{
  const int gw = (int)((blockIdx.x * (unsigned)blockDim.x + threadIdx.x) >> 6); // pixel id
  const int lane = threadIdx.x & 63;
  const int h = (gw >> 7) & 127;
  const int w = gw & 127;
  const float scale = 0.08838834764831845f;   // 1/sqrt(128)

  const int64_t base = (int64_t)gw * D_ + lane * 2;   // lane holds dims 2l,2l+1
  const unsigned int qb = *(const unsigned int*)(Q + base);
  const float qx = bf2f((unsigned short)(qb & 0xFFFFu));
  const float qy = bf2f((unsigned short)(qb >> 16));

  float s[9];
  #pragma unroll
  for (int i = 0; i < 9; ++i){
    const int dy = i / 3 - 1, dx = i % 3 - 1;
    const int h2 = h + dy, w2 = w + dx;
    const bool ok = ((unsigned)h2 < 128u) && ((unsigned)w2 < 128u);
    float partial = 0.f;
    if (ok){
      const int64_t nb = base + (int64_t)(dy * W_ + dx) * D_;
      const unsigned int kb = *(const unsigned int*)(K + nb);
      partial = qx * bf2f((unsigned short)(kb & 0xFFFFu))
              + qy * bf2f((unsigned short)(kb >> 16));
    }
    #pragma unroll
    for (int off = 32; off > 0; off >>= 1)
      partial += __shfl_xor(partial, off, 64);
    // zero-padded reference: OOB neighbor has k=0 -> score exactly 0 (NOT -inf)
    s[i] = ok ? partial * scale : 0.f;
  }

  float m = s[0];
  #pragma unroll
  for (int i = 1; i < 9; ++i) m = fmaxf(m, s[i]);
  float p[9]; float l = 0.f;
  #pragma unroll
  for (int i = 0; i < 9; ++i){ p[i] = __expf(s[i] - m); l += p[i]; }
  const float inv = 1.f / l;

  float ox = 0.f, oy = 0.f;
  #pragma unroll
  for (int i = 0; i < 9; ++i){
    const int dy = i / 3 - 1, dx = i % 3 - 1;
    const int h2 = h + dy, w2 = w + dx;
    if (((unsigned)h2 < 128u) && ((unsigned)w2 < 128u)){
      const int64_t nb = base + (int64_t)(dy * W_ + dx) * D_;
      const unsigned int vb = *(const unsigned int*)(V + nb);
      ox += p[i] * bf2f((unsigned short)(vb & 0xFFFFu));
      oy += p[i] * bf2f((unsigned short)(vb >> 16));
    }
  }
  *(float2*)(out + base) = make_float2(ox * inv, oy * inv);
}

extern "C" void kernel_launch(void* const* d_in, const int* in_sizes, int n_in,
                              void* d_out, int out_size, void* d_ws, size_t ws_size,
                              hipStream_t stream)
{
  const float* x  = (const float*)d_in[0];
  const float* Wq = (const float*)d_in[1];
  const float* bq = (const float*)d_in[2];
  const float* Wk = (const float*)d_in[3];
  const float* bk = (const float*)d_in[4];
  const float* Wv = (const float*)d_in[5];
  const float* bv = (const float*)d_in[6];
  float* out = (float*)d_out;

  char* ws = (char*)d_ws;
  unsigned short* Wt = (unsigned short*)ws;                                   // 96 KB
  unsigned short* Q  = (unsigned short*)(ws + (1<<17));
  unsigned short* K  = (unsigned short*)(ws + (1<<17) + (size_t)M_*D_*2);
  unsigned short* V  = (unsigned short*)(ws + (1<<17) + (size_t)2*M_*D_*2);   // total ~96.1 MB

  hipLaunchKernelGGL(wtrans_kernel, dim3(3), dim3(256), 0, stream, Wq, Wk, Wv, Wt);
  hipLaunchKernelGGL(qkv_gemm_kernel, dim3(3, M_/128), dim3(256), 0, stream,
                     x, Wt, bq, bk, bv, Q, K, V);
  hipLaunchKernelGGL(attn_kernel, dim3(M_/4), dim3(256), 0, stream, Q, K, V, out);
}

// Round 2
// 289.059 us; speedup vs baseline: 1.0649x; 1.0649x over previous
//
#include <hip/hip_runtime.h>
#include <stdint.h>

#define B_ 8
#define H_ 128
#define W_ 128
#define D_ 128
#define N_ (H_*W_)
#define M_ (B_*N_)   // 131072 rows total

typedef __attribute__((ext_vector_type(8))) short short8;
typedef __attribute__((ext_vector_type(4))) float floatx4;

typedef const __attribute__((address_space(1))) void* gas_t;
typedef __attribute__((address_space(3))) void* las_t;

__device__ inline unsigned short f2bf(float f){
  union { float f; unsigned int i; } c; c.f = f;
  unsigned int x = c.i;
  x += 0x7FFF + ((x >> 16) & 1);   // RNE
  return (unsigned short)(x >> 16);
}
__device__ inline float bflo(unsigned int u){  // low bf16 of packed pair -> f32
  union { unsigned int i; float f; } c; c.i = u << 16; return c.f;
}
__device__ inline float bfhi(unsigned int u){  // high bf16 -> f32
  union { unsigned int i; float f; } c; c.i = u & 0xFFFF0000u; return c.f;
}

// ---------------- kernel 0: W -> W^T bf16  ([k][n] fp32 -> [n][k] bf16) ----------------
__global__ void wtrans_kernel(const float* __restrict__ Wq, const float* __restrict__ Wk,
                              const float* __restrict__ Wv, unsigned short* __restrict__ Wt){
  const float* src = blockIdx.x == 0 ? Wq : (blockIdx.x == 1 ? Wk : Wv);
  unsigned short* dst = Wt + blockIdx.x * (D_*D_);
  for (int i = threadIdx.x; i < D_*D_; i += blockDim.x){
    int k = i >> 7, n = i & 127;
    dst[n*D_ + k] = f2bf(src[i]);
  }
}

// ---------------- kernel 1: QKV projection, bf16 MFMA 128x128 tile ----------------
// grid (3, M/128); block 256 (4 waves); wave -> 64x64 quadrant (4x4 of 16x16x32)
// LDS: A [0,16384) ushorts, B [16384,32768). XOR swizzle: 16B chunk c stored at
// c^(row&7) so fragment b128 reads are 2-way bank aliased (free) not 16-way.
__global__ __launch_bounds__(256, 2) void qkv_gemm_kernel(
    const float* __restrict__ x, const unsigned short* __restrict__ Wt,
    const float* __restrict__ bq, const float* __restrict__ bk, const float* __restrict__ bv,
    unsigned short* __restrict__ Q, unsigned short* __restrict__ K, unsigned short* __restrict__ V)
{
  const int which = blockIdx.x;          // 0=Q 1=K 2=V
  const int rowTile = blockIdx.y;
  const float* bias = which == 0 ? bq : (which == 1 ? bk : bv);
  unsigned short* Out = which == 0 ? Q : (which == 1 ? K : V);
  const unsigned short* Wsel = Wt + which * (D_*D_);

  __shared__ unsigned short lds[32768];  // 64 KB -> 2 blocks/CU

  const int t = threadIdx.x;
  const int wave = t >> 6, lane = t & 63;

  // ---- B stage: async global->LDS, 16B/lane. HW dst = uniform base + lane*16.
  {
    const unsigned short* wbase = Wsel;
    #pragma unroll
    for (int p = 0; p < 8; ++p){
      int s = p*256 + t;                 // chunk id (16B units)
      int n = s >> 4, cp = s & 15, c = cp ^ (n & 7);
      const unsigned short* gp = wbase + n*128 + c*8;
      unsigned short* lp = (unsigned short*)lds + 16384 + p*2048 + wave*512; // uniform base
      __builtin_amdgcn_global_load_lds((gas_t)(const void*)gp, (las_t)(void*)lp, 16, 0, 0);
    }
  }
  // ---- A stage: fp32 x -> bf16, swizzled ds_write_b128
  {
    const float* xrow = x + (size_t)rowTile * 128 * D_;
    #pragma unroll
    for (int p = 0; p < 8; ++p){
      int s = p*256 + t;
      int r = s >> 4, cp = s & 15, c = cp ^ (r & 7);
      const float* gp = xrow + r*D_ + c*8;
      float4 f0 = *(const float4*)gp;
      float4 f1 = *(const float4*)(gp + 4);
      uint4 pk;
      pk.x = (unsigned)f2bf(f0.x) | ((unsigned)f2bf(f0.y) << 16);
      pk.y = (unsigned)f2bf(f0.z) | ((unsigned)f2bf(f0.w) << 16);
      pk.z = (unsigned)f2bf(f1.x) | ((unsigned)f2bf(f1.y) << 16);
      pk.w = (unsigned)f2bf(f1.z) | ((unsigned)f2bf(f1.w) << 16);
      *(uint4*)&lds[s*8] = pk;
    }
  }
  __syncthreads();

  const int wm = (wave >> 1) * 64, wn = (wave & 1) * 64;
  const int m0 = lane & 15, quad = lane >> 4;

  floatx4 acc[4][4] = {};
  #pragma unroll
  for (int kk = 0; kk < 4; ++kk){
    short8 a[4], b[4];
    #pragma unroll
    for (int i = 0; i < 4; ++i){
      int row = wm + i*16 + m0;
      int c = (kk*4 + quad) ^ (row & 7);
      a[i] = *(const short8*)&lds[row*128 + c*8];
    }
    #pragma unroll
    for (int j = 0; j < 4; ++j){
      int n = wn + j*16 + m0;
      int c = (kk*4 + quad) ^ (n & 7);
      b[j] = *(const short8*)&lds[16384 + n*128 + c*8];
    }
    #pragma unroll
    for (int i = 0; i < 4; ++i)
      #pragma unroll
      for (int j = 0; j < 4; ++j)
        acc[i][j] = __builtin_amdgcn_mfma_f32_16x16x32_bf16(a[i], b[j], acc[i][j], 0, 0, 0);
  }

  // ---- epilogue: AGPR -> LDS (bf16, +8 ushort pad) -> coalesced 16B global stores
  __syncthreads();
  #pragma unroll
  for (int j = 0; j < 4; ++j){
    const int col = wn + j*16 + m0;
    const float bb = bias[col];
    #pragma unroll
    for (int i = 0; i < 4; ++i){
      #pragma unroll
      for (int r = 0; r < 4; ++r){
        int row = wm + i*16 + quad*4 + r;     // C/D: col=lane&15, row=quad*4+reg
        lds[row*136 + col] = f2bf(acc[i][j][r] + bb);
      }
    }
  }
  __syncthreads();
  unsigned short* Outp = Out + (size_t)rowTile * 128 * D_;
  #pragma unroll
  for (int p = 0; p < 8; ++p){
    int rr = p*16 + (t >> 4), cc = t & 15;
    uint4 v = *(const uint4*)&lds[rr*136 + cc*8];
    *(uint4*)(Outp + p*2048 + t*8) = v;      // lane-contiguous 1KB/instr
  }
}

// ---------------- kernel 2: 3x3 window attention ----------------
// 2 threads per pixel (half = 64 dims each, in registers). One __shfl_xor per
// score instead of a 6-deep butterfly. Block = one image row (128 pixels).
__global__ __launch_bounds__(256) void attn_kernel(
    const unsigned short* __restrict__ Q, const unsigned short* __restrict__ K,
    const unsigned short* __restrict__ V, float* __restrict__ out)
{
  const int t = threadIdx.x;
  const int w = t >> 1, half = t & 1;
  const int bh = blockIdx.x;               // b*128 + h
  const int h = bh & 127;
  const int pix = bh * 128 + w;
  const float scale = 0.08838834764831845f; // 1/sqrt(128)

  // q: 64 dims, pre-scaled
  float q[64];
  {
    const unsigned short* qp = Q + (size_t)pix * D_ + half * 64;
    #pragma unroll
    for (int c = 0; c < 8; ++c){
      uint4 u = *(const uint4*)(qp + c*8);
      unsigned uu[4] = {u.x, u.y, u.z, u.w};
      #pragma unroll
      for (int e = 0; e < 4; ++e){
        q[c*8 + e*2]     = bflo(uu[e]) * scale;
        q[c*8 + e*2 + 1] = bfhi(uu[e]) * scale;
      }
    }
  }

  float s[9];
  #pragma unroll
  for (int i = 0; i < 9; ++i){
    const int dy = i/3 - 1, dx = i%3 - 1;
    const bool ok = ((unsigned)(h + dy) < 128u) && ((unsigned)(w + dx) < 128u);
    float acc = 0.f;
    if (ok){
      const unsigned short* kp = K + (size_t)(pix + dy*W_ + dx) * D_ + half * 64;
      #pragma unroll
      for (int c = 0; c < 8; ++c){
        uint4 u = *(const uint4*)(kp + c*8);
        unsigned uu[4] = {u.x, u.y, u.z, u.w};
        #pragma unroll
        for (int e = 0; e < 4; ++e){
          acc += q[c*8 + e*2]     * bflo(uu[e]);
          acc += q[c*8 + e*2 + 1] * bfhi(uu[e]);
        }
      }
    }
    s[i] = acc;
  }
  // combine the two halves: partner lane = t^1 (same wave)
  #pragma unroll
  for (int i = 0; i < 9; ++i) s[i] += __shfl_xor(s[i], 1, 64);
  // zero-padded reference: OOB score stays exactly 0 (participates in softmax, v=0)

  float m = s[0];
  #pragma unroll
  for (int i = 1; i < 9; ++i) m = fmaxf(m, s[i]);
  float p[9]; float l = 0.f;
  #pragma unroll
  for (int i = 0; i < 9; ++i){ p[i] = __expf(s[i] - m); l += p[i]; }
  const float inv = 1.f / l;

  float o[64];
  #pragma unroll
  for (int d = 0; d < 64; ++d) o[d] = 0.f;
  #pragma unroll
  for (int i = 0; i < 9; ++i){
    const int dy = i/3 - 1, dx = i%3 - 1;
    const bool ok = ((unsigned)(h + dy) < 128u) && ((unsigned)(w + dx) < 128u);
    if (ok){
      const float pi = p[i];
      const unsigned short* vp = V + (size_t)(pix + dy*W_ + dx) * D_ + half * 64;
      #pragma unroll
      for (int c = 0; c < 8; ++c){
        uint4 u = *(const uint4*)(vp + c*8);
        unsigned uu[4] = {u.x, u.y, u.z, u.w};
        #pragma unroll
        for (int e = 0; e < 4; ++e){
          o[c*8 + e*2]     += pi * bflo(uu[e]);
          o[c*8 + e*2 + 1] += pi * bfhi(uu[e]);
        }
      }
    }
  }

  float* op = out + (size_t)pix * D_ + half * 64;
  #pragma unroll
  for (int c = 0; c < 16; ++c){
    float4 v4 = make_float4(o[c*4]*inv, o[c*4+1]*inv, o[c*4+2]*inv, o[c*4+3]*inv);
    *(float4*)(op + c*4) = v4;
  }
}

extern "C" void kernel_launch(void* const* d_in, const int* in_sizes, int n_in,
                              void* d_out, int out_size, void* d_ws, size_t ws_size,
                              hipStream_t stream)
{
  const float* x  = (const float*)d_in[0];
  const float* Wq = (const float*)d_in[1];
  const float* bq = (const float*)d_in[2];
  const float* Wk = (const float*)d_in[3];
  const float* bk = (const float*)d_in[4];
  const float* Wv = (const float*)d_in[5];
  const float* bv = (const float*)d_in[6];
  float* out = (float*)d_out;

  char* ws = (char*)d_ws;
  unsigned short* Wt = (unsigned short*)ws;                                   // 96 KB
  unsigned short* Q  = (unsigned short*)(ws + (1<<17));
  unsigned short* K  = (unsigned short*)(ws + (1<<17) + (size_t)M_*D_*2);
  unsigned short* V  = (unsigned short*)(ws + (1<<17) + (size_t)2*M_*D_*2);   // ~96.1 MB

  hipLaunchKernelGGL(wtrans_kernel, dim3(3), dim3(256), 0, stream, Wq, Wk, Wv, Wt);
  hipLaunchKernelGGL(qkv_gemm_kernel, dim3(3, M_/128), dim3(256), 0, stream,
                     x, Wt, bq, bk, bv, Q, K, V);
  hipLaunchKernelGGL(attn_kernel, dim3(B_*H_), dim3(256), 0, stream, Q, K, V, out);
}

// Round 3
// 220.690 us; speedup vs baseline: 1.3948x; 1.3098x over previous
//
#include <hip/hip_runtime.h>
#include <stdint.h>

#define B_ 8
#define H_ 128
#define W_ 128
#define D_ 128
#define N_ (H_*W_)
#define M_ (B_*N_)   // 131072 rows total

typedef __attribute__((ext_vector_type(8))) short short8;
typedef __attribute__((ext_vector_type(4))) float floatx4;

typedef const __attribute__((address_space(1))) void* gas_t;
typedef __attribute__((address_space(3))) void* las_t;

__device__ inline unsigned short f2bf(float f){
  union { float f; unsigned int i; } c; c.f = f;
  unsigned int x = c.i;
  x += 0x7FFF + ((x >> 16) & 1);   // RNE
  return (unsigned short)(x >> 16);
}
__device__ inline float bflo(unsigned int u){
  union { unsigned int i; float f; } c; c.i = u << 16; return c.f;
}
__device__ inline float bfhi(unsigned int u){
  union { unsigned int i; float f; } c; c.i = u & 0xFFFF0000u; return c.f;
}

// ---------------- kernel 0: W -> W^T bf16, 192 blocks (was 3 -> latency disaster) ----
// grid (3, 64), block 256: one element/thread. Coalesced dword read, 2B scatter write.
__global__ void wtrans_kernel(const float* __restrict__ Wq, const float* __restrict__ Wk,
                              const float* __restrict__ Wv, unsigned short* __restrict__ Wt){
  const float* src = blockIdx.x == 0 ? Wq : (blockIdx.x == 1 ? Wk : Wv);
  unsigned short* dst = Wt + blockIdx.x * (D_*D_);
  const int i = blockIdx.y * 256 + threadIdx.x;
  const int k = i >> 7, n = i & 127;
  dst[n*D_ + k] = f2bf(src[i]);
}

// ---------------- kernel 1: QKV projection, bf16 MFMA 128x128 tile ----------------
// grid (3, M/128); block 256 (4 waves); wave -> 64x64 quadrant (4x4 of 16x16x32)
// LDS: A [0,16384) ushorts, B [16384,32768). XOR swizzle on 16B chunks.
__global__ __launch_bounds__(256, 2) void qkv_gemm_kernel(
    const float* __restrict__ x, const unsigned short* __restrict__ Wt,
    const float* __restrict__ bq, const float* __restrict__ bk, const float* __restrict__ bv,
    unsigned short* __restrict__ Q, unsigned short* __restrict__ K, unsigned short* __restrict__ V)
{
  const int which = blockIdx.x;          // 0=Q 1=K 2=V
  const int rowTile = blockIdx.y;
  const float* bias = which == 0 ? bq : (which == 1 ? bk : bv);
  unsigned short* Out = which == 0 ? Q : (which == 1 ? K : V);
  const unsigned short* Wsel = Wt + which * (D_*D_);

  __shared__ unsigned short lds[32768];  // 64 KB -> 2 blocks/CU

  const int t = threadIdx.x;
  const int wave = t >> 6, lane = t & 63;

  // ---- B stage: async global->LDS, 16B/lane (dst = uniform base + lane*16)
  {
    #pragma unroll
    for (int p = 0; p < 8; ++p){
      int s = p*256 + t;                 // 16B chunk id
      int n = s >> 4, cp = s & 15, c = cp ^ (n & 7);
      const unsigned short* gp = Wsel + n*128 + c*8;
      unsigned short* lp = (unsigned short*)lds + 16384 + p*2048 + wave*512;
      __builtin_amdgcn_global_load_lds((gas_t)(const void*)gp, (las_t)(void*)lp, 16, 0, 0);
    }
  }
  // ---- A stage: fp32 x -> bf16, swizzled ds_write_b128
  {
    const float* xrow = x + (size_t)rowTile * 128 * D_;
    #pragma unroll
    for (int p = 0; p < 8; ++p){
      int s = p*256 + t;
      int r = s >> 4, cp = s & 15, c = cp ^ (r & 7);
      const float* gp = xrow + r*D_ + c*8;
      float4 f0 = *(const float4*)gp;
      float4 f1 = *(const float4*)(gp + 4);
      uint4 pk;
      pk.x = (unsigned)f2bf(f0.x) | ((unsigned)f2bf(f0.y) << 16);
      pk.y = (unsigned)f2bf(f0.z) | ((unsigned)f2bf(f0.w) << 16);
      pk.z = (unsigned)f2bf(f1.x) | ((unsigned)f2bf(f1.y) << 16);
      pk.w = (unsigned)f2bf(f1.z) | ((unsigned)f2bf(f1.w) << 16);
      *(uint4*)&lds[s*8] = pk;
    }
  }
  __syncthreads();

  const int wm = (wave >> 1) * 64, wn = (wave & 1) * 64;
  const int m0 = lane & 15, quad = lane >> 4;

  floatx4 acc[4][4] = {};
  #pragma unroll
  for (int kk = 0; kk < 4; ++kk){
    short8 a[4], b[4];
    #pragma unroll
    for (int i = 0; i < 4; ++i){
      int row = wm + i*16 + m0;
      int c = (kk*4 + quad) ^ (row & 7);
      a[i] = *(const short8*)&lds[row*128 + c*8];
    }
    #pragma unroll
    for (int j = 0; j < 4; ++j){
      int n = wn + j*16 + m0;
      int c = (kk*4 + quad) ^ (n & 7);
      b[j] = *(const short8*)&lds[16384 + n*128 + c*8];
    }
    #pragma unroll
    for (int i = 0; i < 4; ++i)
      #pragma unroll
      for (int j = 0; j < 4; ++j)
        acc[i][j] = __builtin_amdgcn_mfma_f32_16x16x32_bf16(a[i], b[j], acc[i][j], 0, 0, 0);
  }

  // ---- epilogue: AGPR -> LDS (bf16, +8 pad) -> coalesced 16B global stores
  __syncthreads();
  #pragma unroll
  for (int j = 0; j < 4; ++j){
    const int col = wn + j*16 + m0;
    const float bb = bias[col];
    #pragma unroll
    for (int i = 0; i < 4; ++i){
      #pragma unroll
      for (int r = 0; r < 4; ++r){
        int row = wm + i*16 + quad*4 + r;   // C/D: col=lane&15, row=quad*4+reg
        lds[row*136 + col] = f2bf(acc[i][j][r] + bb);
      }
    }
  }
  __syncthreads();
  unsigned short* Outp = Out + (size_t)rowTile * 128 * D_;
  #pragma unroll
  for (int p = 0; p < 8; ++p){
    int rr = p*16 + (t >> 4), cc = t & 15;
    uint4 v = *(const uint4*)&lds[rr*136 + cc*8];
    *(uint4*)(Outp + p*2048 + t*8) = v;
  }
}

// ---------------- kernel 2: 3x3 window attention ----------------
// 4 threads/pixel, 32 dims each -> peak live ~70 VGPRs, no scratch spill
// (round-2 version held 128-float arrays -> spilled: VGPR=60, 36MB spill writes).
// Block 256 = 64 pixels; grid 2048 blocks = 8192 waves = CU capacity.
__global__ __launch_bounds__(256) void attn_kernel(
    const unsigned short* __restrict__ Q, const unsigned short* __restrict__ K,
    const unsigned short* __restrict__ V, float* __restrict__ out)
{
  const int t = threadIdx.x;
  const int quarter = t & 3;               // which 32-dim chunk
  const int pix = blockIdx.x * 64 + (t >> 2);
  const int w = pix & 127;
  const int h = (pix >> 7) & 127;
  const float scale = 0.08838834764831845f; // 1/sqrt(128)

  const size_t off = (size_t)pix * D_ + quarter * 32;

  float q[32];
  {
    const unsigned short* qp = Q + off;
    #pragma unroll
    for (int c = 0; c < 4; ++c){
      uint4 u = *(const uint4*)(qp + c*8);
      unsigned uu[4] = {u.x, u.y, u.z, u.w};
      #pragma unroll
      for (int e = 0; e < 4; ++e){
        q[c*8 + e*2]     = bflo(uu[e]) * scale;
        q[c*8 + e*2 + 1] = bfhi(uu[e]) * scale;
      }
    }
  }

  float s[9];
  #pragma unroll
  for (int i = 0; i < 9; ++i){
    const int dy = i/3 - 1, dx = i%3 - 1;
    const bool ok = ((unsigned)(h + dy) < 128u) && ((unsigned)(w + dx) < 128u);
    float acc = 0.f;
    if (ok){
      const unsigned short* kp = K + off + (dy*W_ + dx) * D_;
      #pragma unroll
      for (int c = 0; c < 4; ++c){
        uint4 u = *(const uint4*)(kp + c*8);
        unsigned uu[4] = {u.x, u.y, u.z, u.w};
        #pragma unroll
        for (int e = 0; e < 4; ++e){
          acc += q[c*8 + e*2]     * bflo(uu[e]);
          acc += q[c*8 + e*2 + 1] * bfhi(uu[e]);
        }
      }
    }
    s[i] = acc;
  }
  // combine 4 quarters (lanes t^1, t^2 within the same pixel group)
  #pragma unroll
  for (int i = 0; i < 9; ++i){
    s[i] += __shfl_xor(s[i], 1, 64);
    s[i] += __shfl_xor(s[i], 2, 64);
  }
  // zero-padded reference: OOB score stays exactly 0 (participates, v=0)

  float m = s[0];
  #pragma unroll
  for (int i = 1; i < 9; ++i) m = fmaxf(m, s[i]);
  float p[9]; float l = 0.f;
  #pragma unroll
  for (int i = 0; i < 9; ++i){ p[i] = __expf(s[i] - m); l += p[i]; }
  const float inv = 1.f / l;

  float o[32];
  #pragma unroll
  for (int d = 0; d < 32; ++d) o[d] = 0.f;
  #pragma unroll
  for (int i = 0; i < 9; ++i){
    const int dy = i/3 - 1, dx = i%3 - 1;
    const bool ok = ((unsigned)(h + dy) < 128u) && ((unsigned)(w + dx) < 128u);
    if (ok){
      const float pi = p[i];
      const unsigned short* vp = V + off + (dy*W_ + dx) * D_;
      #pragma unroll
      for (int c = 0; c < 4; ++c){
        uint4 u = *(const uint4*)(vp + c*8);
        unsigned uu[4] = {u.x, u.y, u.z, u.w};
        #pragma unroll
        for (int e = 0; e < 4; ++e){
          o[c*8 + e*2]     += pi * bflo(uu[e]);
          o[c*8 + e*2 + 1] += pi * bfhi(uu[e]);
        }
      }
    }
  }

  float* op = out + off;
  #pragma unroll
  for (int c = 0; c < 8; ++c){
    float4 v4 = make_float4(o[c*4]*inv, o[c*4+1]*inv, o[c*4+2]*inv, o[c*4+3]*inv);
    *(float4*)(op + c*4) = v4;
  }
}

extern "C" void kernel_launch(void* const* d_in, const int* in_sizes, int n_in,
                              void* d_out, int out_size, void* d_ws, size_t ws_size,
                              hipStream_t stream)
{
  const float* x  = (const float*)d_in[0];
  const float* Wq = (const float*)d_in[1];
  const float* bq = (const float*)d_in[2];
  const float* Wk = (const float*)d_in[3];
  const float* bk = (const float*)d_in[4];
  const float* Wv = (const float*)d_in[5];
  const float* bv = (const float*)d_in[6];
  float* out = (float*)d_out;

  char* ws = (char*)d_ws;
  unsigned short* Wt = (unsigned short*)ws;                                   // 96 KB
  unsigned short* Q  = (unsigned short*)(ws + (1<<17));
  unsigned short* K  = (unsigned short*)(ws + (1<<17) + (size_t)M_*D_*2);
  unsigned short* V  = (unsigned short*)(ws + (1<<17) + (size_t)2*M_*D_*2);   // ~96.1 MB

  hipLaunchKernelGGL(wtrans_kernel, dim3(3, 64), dim3(256), 0, stream, Wq, Wk, Wv, Wt);
  hipLaunchKernelGGL(qkv_gemm_kernel, dim3(3, M_/128), dim3(256), 0, stream,
                     x, Wt, bq, bk, bv, Q, K, V);
  hipLaunchKernelGGL(attn_kernel, dim3(M_/64), dim3(256), 0, stream, Q, K, V, out);
}